// Round 4
// baseline (114.483 us; speedup 1.0000x reference)
//
#include <hip/hip_runtime.h>

#define NB   8
#define S_   1024
#define DIN  1280
#define RANK 64
#define DOUT 1280
#define DOWN (RANK * DIN)          // 81920 floats
#define EMB  (DOWN + DOUT * RANK)  // 163840 floats per batch
#define XSTRIDE 1288               // x LDS row stride (bf16): 2576B, rows step 4 banks

// LDS layout (bytes), total 80896 -> 2 WG/CU
#define XLS_BYTES (16 * XSTRIDE * 2)          // 41216
#define WB_OFF    XLS_BYTES                   // 41216 (16B aligned)
#define WB_BYTES  (2 * 16384)                 // 32768: double-buffered 16KB fp32 chunks
#define PB_OFF    (WB_OFF + WB_BYTES)         // 73984
#define PB_BYTES  (4 * 16 * 17 * 4)           // 4352
#define HL_OFF    (PB_OFF + PB_BYTES)         // 78336
#define HL_BYTES  (16 * 80 * 2)               // 2560
#define LDS_TOTAL (HL_OFF + HL_BYTES)         // 80896

typedef __bf16 bf16x8 __attribute__((ext_vector_type(8)));
typedef __bf16 bf16x4 __attribute__((ext_vector_type(4)));
typedef float  f32x4  __attribute__((ext_vector_type(4)));

__device__ __forceinline__ bf16x8 cvt8(float4 f0, float4 f1) {
    bf16x8 v;
    v[0]=(__bf16)f0.x; v[1]=(__bf16)f0.y; v[2]=(__bf16)f0.z; v[3]=(__bf16)f0.w;
    v[4]=(__bf16)f1.x; v[5]=(__bf16)f1.y; v[6]=(__bf16)f1.z; v[7]=(__bf16)f1.w;
    return v;
}

// coalesced async global->LDS, 16B/lane; LDS dest = wave-uniform base + lane*16
#define GLOAD16(gsrc, ldsoff)                                              \
    __builtin_amdgcn_global_load_lds(                                      \
        (const __attribute__((address_space(1))) void*)(gsrc),             \
        (__attribute__((address_space(3))) void*)(smem + (ldsoff)),        \
        16, 0, 0)

// ---------------- single fused kernel: fp32 weights staged via LDS ----------------
// No workspace, no cvt prepass. Weight chunks are 16KB of *fp32* (k-width 32),
// double-buffered, XOR-swizzled (byte ^= (row&7)<<4) via pre-swizzled global
// source + swizzled LDS reads; fp32->bf16 cvt in registers right before MFMA
// (bit-identical RNE to the old cvt_embed path).
// Phase-1 chunks: [2 kh][64 ranks][32 k] fp32; 20 chunks.
// Phase-2 chunks: [128 out-rows][32 k] fp32; 20 chunks (10 row-groups x 2 k-halves);
// tt=0 chunk staged during phase-1's last iteration (reduce barriers hide it).
__global__ __launch_bounds__(512, 2) void lora_fused(const float* __restrict__ x,
                                                     const float* __restrict__ embed,
                                                     float* __restrict__ out) {
    extern __shared__ char smem[];
    __bf16* xls = (__bf16*)smem;
    float (*pbuf)[16][17] = (float(*)[16][17])(smem + PB_OFF);
    __bf16 (*hld)[80]     = (__bf16(*)[80])(smem + HL_OFF);

    const int b    = blockIdx.x & 7;           // batch pinned per XCD
    const int s0   = (blockIdx.x >> 3) * 16;
    const int t    = threadIdx.x;
    const int w    = t >> 6;
    const int l    = t & 63;
    const int quad = l >> 4;
    const int lc   = l & 15;
    const int dq   = quad * 8;

    const int nt = w & 3;                      // n-tile (16 of 64 ranks)
    const int kh = w >> 2;                     // K half (640 each)

    const char* eb  = (const char*)(embed + (size_t)b * EMB);   // fp32 weight base
    const char* wub = eb + (size_t)DOWN * 4;

    // ---- per-lane pre-swizzled stage sources (linear LDS dest, swizzled source) ----
    const int d0 = w * 2048 + l * 16;          // lane's dest byte in a 16KB chunk
    const int d1 = d0 + 1024;
    // phase 1 decode: d -> [kh(8192B)][r(128B)][colB(128)]
    const int kA = d0 >> 13,        kB = d1 >> 13;
    const int rA = (d0 >> 7) & 63,  rB = (d1 >> 7) & 63;
    const int cA = d0 & 127,        cB = d1 & 127;
    const char* p1a = eb + rA * 5120 + kA * 2560 + (cA ^ ((rA & 7) << 4));
    const char* p1b = eb + rB * 5120 + kB * 2560 + (cB ^ ((rB & 7) << 4));
    // phase 2 decode: d -> [rr(128B)][colB(128)]; chunk (g,kf) adds g*32768 + kf*128
    const int r2A = d0 >> 7,        r2B = d1 >> 7;   // 0..127
    const char* p2a = wub + r2A * 256 + ((d0 & 127) ^ ((r2A & 7) << 4));
    const char* p2b = wub + r2B * 256 + ((d1 & 127) ^ ((r2B & 7) << 4));
    const int ldsA = WB_OFF + w * 2048;        // wave-uniform LDS dest (buf 0)

    // ---- prologue: issue phase-1 chunk 0 (flies under x staging), stage x tile ----
    GLOAD16(p1a, ldsA);
    GLOAD16(p1b, ldsA + 1024);
    {
        const int row = t >> 5;                // 0..15 (32 threads per row)
        const int cc  = t & 31;
        const float4* src = reinterpret_cast<const float4*>(x + (size_t)(b * S_ + s0 + row) * DIN);
        float4 f[10];
#pragma unroll
        for (int j = 0; j < 10; ++j) f[j] = src[cc + 32 * j];   // all 10 in flight
        __bf16* drow = xls + row * XSTRIDE;
#pragma unroll
        for (int j = 0; j < 10; ++j) {
            bf16x4 v;
            v[0]=(__bf16)f[j].x; v[1]=(__bf16)f[j].y; v[2]=(__bf16)f[j].z; v[3]=(__bf16)f[j].w;
            *reinterpret_cast<bf16x4*>(drow + cc * 4 + 128 * j) = v;
        }
    }
    __syncthreads();                           // drains vmcnt: chunk 0 + x ready

    // ---- phase 1: h = x @ w_down^T, 20 fp32 chunks, double-buffered ----
    const __bf16* xrow = xls + lc * XSTRIDE + kh * 640;
    const int brd = kh * 8192 + (nt * 16 + lc) * 128 + quad * 32;  // read byte in chunk
    const int sw  = (lc & 7) << 4;                                  // read-side swizzle
    f32x4 acc = {0,0,0,0};
#pragma unroll
    for (int c = 0; c < 20; ++c) {
        if (c < 19) {
            GLOAD16(p1a + (c + 1) * 128, ((c + 1) & 1) * 16384 + ldsA);
            GLOAD16(p1b + (c + 1) * 128, ((c + 1) & 1) * 16384 + ldsA + 1024);
        } else {                               // stage phase-2 chunk 0 (parity 0 -> buf0)
            GLOAD16(p2a, ldsA);
            GLOAD16(p2b, ldsA + 1024);
        }
        const char* bb = smem + WB_OFF + (c & 1) * 16384;
        bf16x8 af = *reinterpret_cast<const bf16x8*>(xrow + c * 32 + dq);
        float4 w0 = *reinterpret_cast<const float4*>(bb + (brd ^ sw));
        float4 w1 = *reinterpret_cast<const float4*>(bb + ((brd + 16) ^ sw));
        acc = __builtin_amdgcn_mfma_f32_16x16x32_bf16(af, cvt8(w0, w1), acc, 0, 0, 0);
        __syncthreads();
    }

    // ---- kh reduce -> h tile (bf16); barriers also cover phase-2 chunk-0 stage ----
    if (kh == 1) {
#pragma unroll
        for (int i = 0; i < 4; ++i) pbuf[nt][quad * 4 + i][lc] = acc[i];
    }
    __syncthreads();
    if (kh == 0) {
#pragma unroll
        for (int i = 0; i < 4; ++i) {
            float v = acc[i] + pbuf[nt][quad * 4 + i][lc];
            hld[quad * 4 + i][nt * 16 + lc] = (__bf16)v;
        }
    }
    __syncthreads();

    // ---- phase 2: out = h @ w_up^T, 20 fp32 chunks (10 groups x 2 k-halves) ----
    bf16x8 ha0 = *reinterpret_cast<const bf16x8*>(&hld[lc][dq]);
    bf16x8 ha1 = *reinterpret_cast<const bf16x8*>(&hld[lc][32 + dq]);
    float* obase = out + (size_t)(b * S_ + s0 + quad * 4) * DOUT;
    const int rr  = w * 16 + lc;
    const int prd = rr * 128 + quad * 32;      // read byte in chunk

    f32x4 c4 = {0,0,0,0};
#pragma unroll
    for (int t2 = 0; t2 < 20; ++t2) {
        if (t2 < 19) {
            const int nx = t2 + 1;
            GLOAD16(p2a + (nx >> 1) * 32768 + (nx & 1) * 128, (nx & 1) * 16384 + ldsA);
            GLOAD16(p2b + (nx >> 1) * 32768 + (nx & 1) * 128, (nx & 1) * 16384 + ldsA + 1024);
        }
        const char* bb = smem + WB_OFF + (t2 & 1) * 16384;
        float4 w0 = *reinterpret_cast<const float4*>(bb + (prd ^ sw));
        float4 w1 = *reinterpret_cast<const float4*>(bb + ((prd + 16) ^ sw));
        c4 = __builtin_amdgcn_mfma_f32_16x16x32_bf16((t2 & 1) ? ha1 : ha0, cvt8(w0, w1), c4, 0, 0, 0);
        if (t2 & 1) {                          // finished k for this row-group: store
            const int o = (t2 >> 1) * 128 + rr;
#pragma unroll
            for (int i = 0; i < 4; ++i)
                obase[(size_t)i * DOUT + o] = c4[i];
            c4[0]=0.f; c4[1]=0.f; c4[2]=0.f; c4[3]=0.f;
        }
        if (t2 < 19) __syncthreads();
    }
}

extern "C" void kernel_launch(void* const* d_in, const int* in_sizes, int n_in,
                              void* d_out, int out_size, void* d_ws, size_t ws_size,
                              hipStream_t stream) {
    const float* x     = (const float*)d_in[0];
    const float* embed = (const float*)d_in[1];
    float*       out   = (float*)d_out;
    (void)in_sizes; (void)n_in; (void)out_size; (void)d_ws; (void)ws_size;

    lora_fused<<<dim3(512), dim3(512), LDS_TOTAL, stream>>>(x, embed, out);
}

// Round 8
// 101.573 us; speedup vs baseline: 1.1271x; 1.1271x over previous
//
#include <hip/hip_runtime.h>

#define NB   8
#define S_   1024
#define DIN  1280
#define RANK 64
#define DOUT 1280
#define DOWN (RANK * DIN)          // 81920
#define EMB  (DOWN + DOUT * RANK)  // 163840
#define XSTRIDE 1288               // x LDS row stride (bf16): 2576B, rows step 4 banks

// LDS layout (bytes), total 80896 -> 2 WG/CU
#define XLS_OFF   0
#define XLS_BYTES (16 * XSTRIDE * 2)          // 41216
#define WB_OFF    XLS_BYTES                   // 41216 (16B aligned)
#define WB_BYTES  (2 * 16384)                 // 32768: double-buffered 16KB weight chunks
#define PB_OFF    (WB_OFF + WB_BYTES)         // 73984
#define PB_BYTES  (4 * 16 * 17 * 4)           // 4352
#define HL_OFF    (PB_OFF + PB_BYTES)         // 78336
#define HL_BYTES  (16 * 80 * 2)               // 2560
#define LDS_TOTAL (HL_OFF + HL_BYTES)         // 80896

typedef __bf16 bf16x8 __attribute__((ext_vector_type(8)));
typedef __bf16 bf16x4 __attribute__((ext_vector_type(4)));
typedef float  f32x4  __attribute__((ext_vector_type(4)));

// coalesced async global->LDS, 16B/lane; LDS dest = uniform base + lane*16
#define GLOAD16(gsrc, ldsoff)                                              \
    __builtin_amdgcn_global_load_lds(                                      \
        (const __attribute__((address_space(1))) void*)(gsrc),             \
        (__attribute__((address_space(3))) void*)(smem + (ldsoff)),        \
        16, 0, 0)

// ---------------- prep: embed fp32 -> bf16 (into d_ws) ----------------
__global__ __launch_bounds__(256) void cvt_embed(const float* __restrict__ src,
                                                 __bf16* __restrict__ dst, int n8) {
    const int i = blockIdx.x * 256 + threadIdx.x;
    if (i < n8) {
        const float4* s = reinterpret_cast<const float4*>(src) + (size_t)i * 2;
        float4 f0 = s[0], f1 = s[1];
        bf16x8 v;
        v[0]=(__bf16)f0.x; v[1]=(__bf16)f0.y; v[2]=(__bf16)f0.z; v[3]=(__bf16)f0.w;
        v[4]=(__bf16)f1.x; v[5]=(__bf16)f1.y; v[6]=(__bf16)f1.z; v[7]=(__bf16)f1.w;
        *reinterpret_cast<bf16x8*>(dst + (size_t)i * 8) = v;
    }
}

// ---------------- main: R3 structure (proven) — all weight fragments via LDS ----------------
// Phase-1 chunks: [2 kh][64 ranks][64 k] bf16 = 16KB, double-buffered, XOR-swizzled
// (byte ^= (row&7)<<4) via pre-swizzled global source + swizzled ds_read.
// Phase-2 chunks: [128 out-rows][64 k] bf16 = 16KB, same treatment; tt=0 staged
// during phase-1's last iteration (reduce barriers hide its latency).
// Synchronization: __syncthreads() only (full drain semantics — race-proof; the
// counted-vmcnt variants raced twice under hipcc reordering and were abandoned).
__global__ __launch_bounds__(512, 2) void lora_main(const float* __restrict__ x,
                                                    const __bf16* __restrict__ ew,
                                                    float* __restrict__ out) {
    extern __shared__ char smem[];
    __bf16* xls = (__bf16*)(smem + XLS_OFF);
    float (*pbuf)[16][17] = (float(*)[16][17])(smem + PB_OFF);
    __bf16 (*hld)[80]     = (__bf16(*)[80])(smem + HL_OFF);

    const int b    = blockIdx.x & 7;           // batch pinned per XCD
    const int s0   = (blockIdx.x >> 3) * 16;
    const int t    = threadIdx.x;
    const int w    = t >> 6;
    const int l    = t & 63;
    const int quad = l >> 4;
    const int lc   = l & 15;
    const int dq   = quad * 8;

    const int nt = w & 3;                      // n-tile (16 of 64 ranks)
    const int kh = w >> 2;                     // K half (640 each)

    // ---- per-lane pre-swizzled stage sources (rule #21: linear dest, swz source) ----
    const char* wdB = (const char*)(ew + (size_t)b * EMB);
    const char* wuB = wdB + (size_t)DOWN * 2;
    const int d0 = w * 2048 + l * 16;          // this lane's dest byte in a 16KB chunk
    const int d1 = d0 + 1024;
    // phase 1 decode: d -> [kh][r(64)][colB(128)]
    const int kh0 = d0 >> 13,        kh1 = d1 >> 13;
    const int r0  = (d0 >> 7) & 63,  r1  = (d1 >> 7) & 63;
    const int cB0 = d0 & 127,        cB1 = d1 & 127;
    const char* p1a = wdB + r0 * 2560 + kh0 * 1280 + (cB0 ^ ((r0 & 7) << 4));
    const char* p1b = wdB + r1 * 2560 + kh1 * 1280 + (cB1 ^ ((r1 & 7) << 4));
    // phase 2 decode: d -> [r(128)][colB(128)]; rows contiguous (128B each)
    const char* p2a = wuB + (d0 ^ (((d0 >> 7) & 7) << 4));
    const char* p2b = wuB + (d1 ^ (((d1 >> 7) & 7) << 4));
    const int ldsA = WB_OFF + w * 2048;        // wave-uniform LDS dest (buf 0)
    const int bswz = (lc & 7) << 4;            // read-side swizzle

    // ---- prologue: issue w chunk 0 (in flight under x staging), stage x tile ----
    GLOAD16(p1a, ldsA);
    GLOAD16(p1b, ldsA + 1024);
    {
        const int row = t >> 5;                // 0..15 (32 threads per row)
        const int c   = t & 31;
        const float4* src = reinterpret_cast<const float4*>(x + (size_t)(b * S_ + s0 + row) * DIN);
        float4 f[10];
#pragma unroll
        for (int j = 0; j < 10; ++j) f[j] = src[c + 32 * j];   // all 10 in flight
        __bf16* drow = xls + row * XSTRIDE;
#pragma unroll
        for (int j = 0; j < 10; ++j) {
            bf16x4 v;
            v[0]=(__bf16)f[j].x; v[1]=(__bf16)f[j].y; v[2]=(__bf16)f[j].z; v[3]=(__bf16)f[j].w;
            *reinterpret_cast<bf16x4*>(drow + c * 4 + 128 * j) = v;
        }
    }
    __syncthreads();                           // drains vmcnt: chunk 0 + x ready

    // ---- phase 1: h = x @ w_down^T, LDS-staged weights, 2-phase pipeline ----
    const __bf16* xrow = xls + lc * XSTRIDE + kh * 640;
    const int brow = kh * 8192 + (nt * 16 + lc) * 128;   // byte offset in chunk
    f32x4 acc = {0,0,0,0};
#pragma unroll
    for (int c = 0; c < 10; ++c) {
        const int nb = (c & 1) ^ 1;
        if (c < 9) {                           // stage next chunk into other buffer
            GLOAD16(p1a + (c + 1) * 128, nb * 16384 + ldsA);
            GLOAD16(p1b + (c + 1) * 128, nb * 16384 + ldsA + 1024);
        } else {                               // stage phase-2 tt=0 (nb==0 -> buf0)
            GLOAD16(p2a, ldsA);
            GLOAD16(p2b, ldsA + 1024);
        }
        const char* bb = smem + WB_OFF + (c & 1) * 16384;
#pragma unroll
        for (int j = 0; j < 2; ++j) {
            bf16x8 af = *reinterpret_cast<const bf16x8*>(xrow + c * 64 + j * 32 + dq);
            bf16x8 bf = *reinterpret_cast<const bf16x8*>(bb + ((brow + j * 64 + quad * 16) ^ bswz));
            acc = __builtin_amdgcn_mfma_f32_16x16x32_bf16(af, bf, acc, 0, 0, 0);
        }
        __syncthreads();                       // next chunk staged + buffers safe
    }

    // ---- kh reduce -> h tile (bf16); barriers also cover tt=0 stage ----
    if (kh == 1) {
#pragma unroll
        for (int i = 0; i < 4; ++i) pbuf[nt][quad * 4 + i][lc] = acc[i];
    }
    __syncthreads();
    if (kh == 0) {
#pragma unroll
        for (int i = 0; i < 4; ++i) {
            float v = acc[i] + pbuf[nt][quad * 4 + i][lc];
            hld[quad * 4 + i][nt * 16 + lc] = (__bf16)v;
        }
    }
    __syncthreads();

    // ---- phase 2: out = h @ w_up^T, LDS-staged weights ----
    bf16x8 ha0 = *reinterpret_cast<const bf16x8*>(&hld[lc][dq]);
    bf16x8 ha1 = *reinterpret_cast<const bf16x8*>(&hld[lc][32 + dq]);
    float* obase = out + (size_t)(b * S_ + s0 + quad * 4) * DOUT;
    const int prow = (w * 16 + lc) * 128;      // byte offset in chunk

#pragma unroll
    for (int tt = 0; tt < 10; ++tt) {
        if (tt < 9) {
            const int nb = (tt & 1) ^ 1;
            GLOAD16(p2a + (tt + 1) * 16384, nb * 16384 + ldsA);
            GLOAD16(p2b + (tt + 1) * 16384, nb * 16384 + ldsA + 1024);
        }
        const char* bb = smem + WB_OFF + (tt & 1) * 16384;
        bf16x8 b0 = *reinterpret_cast<const bf16x8*>(bb + ((prow + quad * 16) ^ bswz));
        bf16x8 b1 = *reinterpret_cast<const bf16x8*>(bb + ((prow + 64 + quad * 16) ^ bswz));
        f32x4 c4 = {0,0,0,0};
        c4 = __builtin_amdgcn_mfma_f32_16x16x32_bf16(ha0, b0, c4, 0, 0, 0);
        c4 = __builtin_amdgcn_mfma_f32_16x16x32_bf16(ha1, b1, c4, 0, 0, 0);
        const int o = (w + 8 * tt) * 16 + lc;
#pragma unroll
        for (int i = 0; i < 4; ++i)
            obase[(size_t)i * DOUT + o] = c4[i];
        if (tt < 9) __syncthreads();
    }
}

extern "C" void kernel_launch(void* const* d_in, const int* in_sizes, int n_in,
                              void* d_out, int out_size, void* d_ws, size_t ws_size,
                              hipStream_t stream) {
    const float* x     = (const float*)d_in[0];
    const float* embed = (const float*)d_in[1];
    float*       out   = (float*)d_out;
    __bf16*      ew    = (__bf16*)d_ws;        // 8 x 163840 bf16 = 2.6 MB
    (void)in_sizes; (void)n_in; (void)out_size; (void)ws_size;

    cvt_embed<<<dim3(640), dim3(256), 0, stream>>>(embed, ew, NB * EMB / 8);
    lora_main<<<dim3(512), dim3(512), LDS_TOTAL, stream>>>(x, ew, out);
}